// Round 16
// baseline (591.409 us; speedup 1.0000x reference)
//
#include <hip/hip_runtime.h>

#define N_   128
#define C_   12
#define L_   2048
#define H_   32
#define K_   8
#define CP_  6
#define KW_  9
#define FEAT_ 8192   // D*DIV*2*H*K

template<int DIL, bool GUARD>
__device__ __forceinline__ void conv_phase(const float* __restrict__ s,
                                           const float* __restrict__ wr,
                                           float* __restrict__ cx,
                                           int* __restrict__ cn,
                                           const int tid)
{
    if constexpr (DIL == 1) {
        // sliding 12-float window, 2 groups of 4 consecutive positions
        #pragma unroll
        for (int g = 0; g < 2; ++g) {
            const int t = g * 1024 + 4 * tid;
            float win[12];
            #pragma unroll
            for (int q = 0; q < 3; ++q) {
                const float4 v = *(const float4*)(s + t + 4 * q);  // ds_read_b128
                win[4*q+0] = v.x; win[4*q+1] = v.y;
                win[4*q+2] = v.z; win[4*q+3] = v.w;
            }
            #pragma unroll
            for (int p = 0; p < 4; ++p) {
                if (GUARD && g == 1 && p == 3 && tid == 255) continue;  // pos 2047
                float a0 = 0.f, a1 = 0.f, a2 = 0.f, a3 = 0.f,
                      a4 = 0.f, a5 = 0.f, a6 = 0.f, a7 = 0.f;
                #pragma unroll
                for (int w = 0; w < KW_; ++w) {
                    const float v = win[p + w];
                    a0 = fmaf(v, wr[0 * KW_ + w], a0);
                    a1 = fmaf(v, wr[1 * KW_ + w], a1);
                    a2 = fmaf(v, wr[2 * KW_ + w], a2);
                    a3 = fmaf(v, wr[3 * KW_ + w], a3);
                    a4 = fmaf(v, wr[4 * KW_ + w], a4);
                    a5 = fmaf(v, wr[5 * KW_ + w], a5);
                    a6 = fmaf(v, wr[6 * KW_ + w], a6);
                    a7 = fmaf(v, wr[7 * KW_ + w], a7);
                }
                const float mxa = fmaxf(fmaxf(a0, a1), a2);
                const float mxb = fmaxf(fmaxf(a3, a4), a5);
                const float mxc = fmaxf(fmaxf(a6, a7), mxa);
                const float mx  = fmaxf(mxb, mxc);
                const float mna = fminf(fminf(a0, a1), a2);
                const float mnb = fminf(fminf(a3, a4), a5);
                const float mnc = fminf(fminf(a6, a7), mna);
                const float mn  = fminf(mnb, mnc);
                cx[0] += (a0 == mx) ? a0 : 0.f;  cn[0] += (a0 == mn);
                cx[1] += (a1 == mx) ? a1 : 0.f;  cn[1] += (a1 == mn);
                cx[2] += (a2 == mx) ? a2 : 0.f;  cn[2] += (a2 == mn);
                cx[3] += (a3 == mx) ? a3 : 0.f;  cn[3] += (a3 == mn);
                cx[4] += (a4 == mx) ? a4 : 0.f;  cn[4] += (a4 == mn);
                cx[5] += (a5 == mx) ? a5 : 0.f;  cn[5] += (a5 == mn);
                cx[6] += (a6 == mx) ? a6 : 0.f;  cn[6] += (a6 == mn);
                cx[7] += (a7 == mx) ? a7 : 0.f;  cn[7] += (a7 == mn);
            }
        }
    } else {
        // 4 subgroups x 2 consecutive positions; 9 float2 window (18 regs)
        #pragma unroll
        for (int g = 0; g < 4; ++g) {
            const int t = g * 512 + 2 * tid;
            float2 wv[9];
            #pragma unroll
            for (int w = 0; w < KW_; ++w)
                wv[w] = *(const float2*)(s + t + w * DIL);   // ds_read_b64
            #pragma unroll
            for (int p = 0; p < 2; ++p) {
                if (GUARD && g == 3 && p == 1 && tid == 255) continue;  // pos 2047
                float a0 = 0.f, a1 = 0.f, a2 = 0.f, a3 = 0.f,
                      a4 = 0.f, a5 = 0.f, a6 = 0.f, a7 = 0.f;
                #pragma unroll
                for (int w = 0; w < KW_; ++w) {
                    const float v = p ? wv[w].y : wv[w].x;
                    a0 = fmaf(v, wr[0 * KW_ + w], a0);
                    a1 = fmaf(v, wr[1 * KW_ + w], a1);
                    a2 = fmaf(v, wr[2 * KW_ + w], a2);
                    a3 = fmaf(v, wr[3 * KW_ + w], a3);
                    a4 = fmaf(v, wr[4 * KW_ + w], a4);
                    a5 = fmaf(v, wr[5 * KW_ + w], a5);
                    a6 = fmaf(v, wr[6 * KW_ + w], a6);
                    a7 = fmaf(v, wr[7 * KW_ + w], a7);
                }
                const float mxa = fmaxf(fmaxf(a0, a1), a2);
                const float mxb = fmaxf(fmaxf(a3, a4), a5);
                const float mxc = fmaxf(fmaxf(a6, a7), mxa);
                const float mx  = fmaxf(mxb, mxc);
                const float mna = fminf(fminf(a0, a1), a2);
                const float mnb = fminf(fminf(a3, a4), a5);
                const float mnc = fminf(fminf(a6, a7), mna);
                const float mn  = fminf(mnb, mnc);
                cx[0] += (a0 == mx) ? a0 : 0.f;  cn[0] += (a0 == mn);
                cx[1] += (a1 == mx) ? a1 : 0.f;  cn[1] += (a1 == mn);
                cx[2] += (a2 == mx) ? a2 : 0.f;  cn[2] += (a2 == mn);
                cx[3] += (a3 == mx) ? a3 : 0.f;  cn[3] += (a3 == mn);
                cx[4] += (a4 == mx) ? a4 : 0.f;  cn[4] += (a4 == mn);
                cx[5] += (a5 == mx) ? a5 : 0.f;  cn[5] += (a5 == mn);
                cx[6] += (a6 == mx) ? a6 : 0.f;  cn[6] += (a6 == mn);
                cx[7] += (a7 == mx) ? a7 : 0.f;  cn[7] += (a7 == mn);
            }
        }
    }
}

// R15 lesson: 5 waves (VGPR cap 48) spills + degrades schedule; 4 waves @64 VGPR
// is the sweet spot. This round: barrier diet (4-6 -> 2 per block).
__global__ __launch_bounds__(256, 4) void hydra_kernel(
    const float* __restrict__ X,   // [N, C, L]
    const float* __restrict__ W,   // [D, DIV, K*H, 1, KW]
    const int*   __restrict__ I,   // [D, DIV, H, CP]
    float* __restrict__ out)       // [N, FEAT]
{
    __shared__ __align__(16) float s_conv[3072];   // padded conv input
    __shared__ __align__(16) float s_red[4352];    // 16x16x17 reduce matrix

    const int tid   = threadIdx.x;
    // ---- XCD-aware swizzle (T1): XCD k = blockIdx%8 owns n in [16k, 16k+16) ----
    const int b_raw = blockIdx.x;
    const int xcd   = b_raw & 7;
    const int sub   = b_raw >> 3;          // 0..8191
    const int n     = xcd * 16 + (sub >> 9);
    const int rem   = sub & 511;
    const int comb  = rem >> 5;            // di*2 + df
    const int h     = rem & 31;

    const int df   = comb & 1;
    const int di   = comb >> 1;
    const int d    = 1 << di;
    const int Lsrc = L_ - df;              // 2048 or 2047
    const int pad  = 4 * d;

    // ---- zero ONLY the pad regions (disjoint from staging writes -> no barrier) ----
    for (int j = tid; j < pad; j += 256)              s_conv[j] = 0.0f;
    for (int j = pad + Lsrc + tid; j < 3072; j += 256) s_conv[j] = 0.0f;

    // block-uniform channel indices (scalarized)
    const int* Ib = I + (comb * H_ + h) * CP_;
    const int c0 = Ib[0], c1 = Ib[1], c2 = Ib[2],
              c3 = Ib[3], c4 = Ib[4], c5 = Ib[5];
    const float* Xn = X + (size_t)n * (C_ * L_);
    const float* xp0 = Xn + c0 * L_;
    const float* xp1 = Xn + c1 * L_;
    const float* xp2 = Xn + c2 * L_;
    const float* xp3 = Xn + c3 * L_;
    const float* xp4 = Xn + c4 * L_;
    const float* xp5 = Xn + c5 * L_;

    // block-uniform weights -> SGPRs
    const float* Wb = W + (size_t)(comb * (K_ * H_) + h * K_) * KW_;
    float wr[K_ * KW_];
    #pragma unroll
    for (int q = 0; q < K_ * KW_; ++q) wr[q] = Wb[q];

    // ---- staging: burst loads; df=1 fuses diff (loads at t and t+1, both cached) ----
    {
        float sl[8];
        {
            float l0[8], l1[8], l2[8];
            #pragma unroll
            for (int i = 0; i < 8; ++i) {
                const int t = tid + i * 256;
                l0[i] = xp0[t]; l1[i] = xp1[t]; l2[i] = xp2[t];
            }
            #pragma unroll
            for (int i = 0; i < 8; ++i) sl[i] = (l0[i] + l1[i]) + l2[i];
        }
        {
            float l0[8], l1[8], l2[8];
            #pragma unroll
            for (int i = 0; i < 8; ++i) {
                const int t = tid + i * 256;
                l0[i] = xp3[t]; l1[i] = xp4[t]; l2[i] = xp5[t];
            }
            #pragma unroll
            for (int i = 0; i < 8; ++i) sl[i] += (l0[i] + l1[i]) + l2[i];
        }
        if (df == 0) {
            #pragma unroll
            for (int i = 0; i < 8; ++i)
                s_conv[pad + tid + i * 256] = sl[i];
        } else {
            float sr[8];
            {
                float r0[8], r1[8], r2[8];
                #pragma unroll
                for (int i = 0; i < 8; ++i) {
                    const int t  = tid + i * 256;
                    const int t1 = (t < 2047) ? t + 1 : 2047;   // clamp: avoid OOB
                    r0[i] = xp0[t1]; r1[i] = xp1[t1]; r2[i] = xp2[t1];
                }
                #pragma unroll
                for (int i = 0; i < 8; ++i) sr[i] = (r0[i] + r1[i]) + r2[i];
            }
            {
                float r0[8], r1[8], r2[8];
                #pragma unroll
                for (int i = 0; i < 8; ++i) {
                    const int t  = tid + i * 256;
                    const int t1 = (t < 2047) ? t + 1 : 2047;
                    r0[i] = xp3[t1]; r1[i] = xp4[t1]; r2[i] = xp5[t1];
                }
                #pragma unroll
                for (int i = 0; i < 8; ++i) sr[i] += (r0[i] + r1[i]) + r2[i];
            }
            // D[t] = S[t+1]-S[t] == sum of channel diffs; position 2047 not in Lsrc
            #pragma unroll
            for (int i = 0; i < 8; ++i) {
                const int t = tid + i * 256;
                s_conv[pad + t] = (i == 7 && tid == 255) ? 0.0f : (sr[i] - sl[i]);
            }
        }
    }
    __syncthreads();   // barrier 1: staging + pad-zeros visible

    // ---- conv + equality-scatter (templated dilation) ----
    float cx[K_] = {0.f, 0.f, 0.f, 0.f, 0.f, 0.f, 0.f, 0.f};
    int   cn[K_] = {0, 0, 0, 0, 0, 0, 0, 0};

    switch (comb) {
        case  0: conv_phase<  1, false>(s_conv, wr, cx, cn, tid); break;
        case  1: conv_phase<  1, true >(s_conv, wr, cx, cn, tid); break;
        case  2: conv_phase<  2, false>(s_conv, wr, cx, cn, tid); break;
        case  3: conv_phase<  2, true >(s_conv, wr, cx, cn, tid); break;
        case  4: conv_phase<  4, false>(s_conv, wr, cx, cn, tid); break;
        case  5: conv_phase<  4, true >(s_conv, wr, cx, cn, tid); break;
        case  6: conv_phase<  8, false>(s_conv, wr, cx, cn, tid); break;
        case  7: conv_phase<  8, true >(s_conv, wr, cx, cn, tid); break;
        case  8: conv_phase< 16, false>(s_conv, wr, cx, cn, tid); break;
        case  9: conv_phase< 16, true >(s_conv, wr, cx, cn, tid); break;
        case 10: conv_phase< 32, false>(s_conv, wr, cx, cn, tid); break;
        case 11: conv_phase< 32, true >(s_conv, wr, cx, cn, tid); break;
        case 12: conv_phase< 64, false>(s_conv, wr, cx, cn, tid); break;
        case 13: conv_phase< 64, true >(s_conv, wr, cx, cn, tid); break;
        case 14: conv_phase<128, false>(s_conv, wr, cx, cn, tid); break;
        default: conv_phase<128, true >(s_conv, wr, cx, cn, tid); break;
    }

    // ---- reduce matrix write: s_red disjoint from s_conv -> no barrier needed ----
    {
        const int wc = tid >> 4;   // 0..15
        const int wu = tid & 15;   // 0..15
        #pragma unroll
        for (int k = 0; k < K_; ++k) {
            s_red[((k     ) * 16 + wc) * 17 + wu] = cx[k];
            s_red[((k + 8 ) * 16 + wc) * 17 + wu] = (float)cn[k];
        }
    }
    __syncthreads();   // barrier 2: reduce writes visible

    {
        const int r = tid >> 4;    // accumulator id 0..15
        const int c = tid & 15;    // chunk id 0..15
        const int base = (r * 16 + c) * 17;
        float p = 0.f;
        #pragma unroll
        for (int u = 0; u < 16; ++u)
            p += s_red[base + u];
        #pragma unroll
        for (int off = 1; off < 16; off <<= 1)
            p += __shfl_xor(p, off, 64);
        if (c == 0) {
            const int s = r >> 3;      // 0 = cmax, 1 = cmin
            const int k = r & 7;
            out[(size_t)n * FEAT_ + (comb * 2 + s) * (H_ * K_) + h * K_ + k] = p;
        }
    }
}

extern "C" void kernel_launch(void* const* d_in, const int* in_sizes, int n_in,
                              void* d_out, int out_size, void* d_ws, size_t ws_size,
                              hipStream_t stream) {
    const float* X = (const float*)d_in[0];
    const float* W = (const float*)d_in[1];
    const int*   I = (const int*)d_in[2];
    float* out = (float*)d_out;

    const int blocks = N_ * 16 * H_;   // 65536: (n, di, df, h)
    hipLaunchKernelGGL(hydra_kernel, dim3(blocks), dim3(256), 0, stream,
                       X, W, I, out);
}

// Round 17
// 385.306 us; speedup vs baseline: 1.5349x; 1.5349x over previous
//
#include <hip/hip_runtime.h>

#define N_   128
#define C_   12
#define L_   2048
#define H_   32
#define K_   8
#define CP_  6
#define KW_  9
#define FEAT_ 8192   // D*DIV*2*H*K

template<int DIL, bool GUARD>
__device__ __forceinline__ void conv_phase(const float* __restrict__ s,
                                           const float* __restrict__ wr,
                                           float* __restrict__ cx,
                                           int* __restrict__ cn,
                                           const int lane)
{
    if constexpr (DIL == 1) {
        // 8 groups x 4 consecutive positions per lane (t = g*256 + 4*lane)
        #pragma unroll 2
        for (int g = 0; g < 8; ++g) {
            const int t = g * 256 + 4 * lane;
            float win[12];
            #pragma unroll
            for (int q = 0; q < 3; ++q) {
                const float4 v = *(const float4*)(s + t + 4 * q);  // ds_read_b128
                win[4*q+0] = v.x; win[4*q+1] = v.y;
                win[4*q+2] = v.z; win[4*q+3] = v.w;
            }
            #pragma unroll
            for (int p = 0; p < 4; ++p) {
                if (GUARD && g == 7 && p == 3 && lane == 63) continue;  // pos 2047
                float a0 = 0.f, a1 = 0.f, a2 = 0.f, a3 = 0.f,
                      a4 = 0.f, a5 = 0.f, a6 = 0.f, a7 = 0.f;
                #pragma unroll
                for (int w = 0; w < KW_; ++w) {
                    const float v = win[p + w];
                    a0 = fmaf(v, wr[0 * KW_ + w], a0);
                    a1 = fmaf(v, wr[1 * KW_ + w], a1);
                    a2 = fmaf(v, wr[2 * KW_ + w], a2);
                    a3 = fmaf(v, wr[3 * KW_ + w], a3);
                    a4 = fmaf(v, wr[4 * KW_ + w], a4);
                    a5 = fmaf(v, wr[5 * KW_ + w], a5);
                    a6 = fmaf(v, wr[6 * KW_ + w], a6);
                    a7 = fmaf(v, wr[7 * KW_ + w], a7);
                }
                const float mxa = fmaxf(fmaxf(a0, a1), a2);
                const float mxb = fmaxf(fmaxf(a3, a4), a5);
                const float mxc = fmaxf(fmaxf(a6, a7), mxa);
                const float mx  = fmaxf(mxb, mxc);
                const float mna = fminf(fminf(a0, a1), a2);
                const float mnb = fminf(fminf(a3, a4), a5);
                const float mnc = fminf(fminf(a6, a7), mna);
                const float mn  = fminf(mnb, mnc);
                cx[0] += (a0 == mx) ? a0 : 0.f;  cn[0] += (a0 == mn);
                cx[1] += (a1 == mx) ? a1 : 0.f;  cn[1] += (a1 == mn);
                cx[2] += (a2 == mx) ? a2 : 0.f;  cn[2] += (a2 == mn);
                cx[3] += (a3 == mx) ? a3 : 0.f;  cn[3] += (a3 == mn);
                cx[4] += (a4 == mx) ? a4 : 0.f;  cn[4] += (a4 == mn);
                cx[5] += (a5 == mx) ? a5 : 0.f;  cn[5] += (a5 == mn);
                cx[6] += (a6 == mx) ? a6 : 0.f;  cn[6] += (a6 == mn);
                cx[7] += (a7 == mx) ? a7 : 0.f;  cn[7] += (a7 == mn);
            }
        }
    } else {
        // 16 groups x 2 consecutive positions per lane (t = g*128 + 2*lane)
        #pragma unroll 4
        for (int g = 0; g < 16; ++g) {
            const int t = g * 128 + 2 * lane;
            float2 wv[9];
            #pragma unroll
            for (int w = 0; w < KW_; ++w)
                wv[w] = *(const float2*)(s + t + w * DIL);   // ds_read_b64
            #pragma unroll
            for (int p = 0; p < 2; ++p) {
                if (GUARD && g == 15 && p == 1 && lane == 63) continue;  // pos 2047
                float a0 = 0.f, a1 = 0.f, a2 = 0.f, a3 = 0.f,
                      a4 = 0.f, a5 = 0.f, a6 = 0.f, a7 = 0.f;
                #pragma unroll
                for (int w = 0; w < KW_; ++w) {
                    const float v = p ? wv[w].y : wv[w].x;
                    a0 = fmaf(v, wr[0 * KW_ + w], a0);
                    a1 = fmaf(v, wr[1 * KW_ + w], a1);
                    a2 = fmaf(v, wr[2 * KW_ + w], a2);
                    a3 = fmaf(v, wr[3 * KW_ + w], a3);
                    a4 = fmaf(v, wr[4 * KW_ + w], a4);
                    a5 = fmaf(v, wr[5 * KW_ + w], a5);
                    a6 = fmaf(v, wr[6 * KW_ + w], a6);
                    a7 = fmaf(v, wr[7 * KW_ + w], a7);
                }
                const float mxa = fmaxf(fmaxf(a0, a1), a2);
                const float mxb = fmaxf(fmaxf(a3, a4), a5);
                const float mxc = fmaxf(fmaxf(a6, a7), mxa);
                const float mx  = fmaxf(mxb, mxc);
                const float mna = fminf(fminf(a0, a1), a2);
                const float mnb = fminf(fminf(a3, a4), a5);
                const float mnc = fminf(fminf(a6, a7), mna);
                const float mn  = fminf(mnb, mnc);
                cx[0] += (a0 == mx) ? a0 : 0.f;  cn[0] += (a0 == mn);
                cx[1] += (a1 == mx) ? a1 : 0.f;  cn[1] += (a1 == mn);
                cx[2] += (a2 == mx) ? a2 : 0.f;  cn[2] += (a2 == mn);
                cx[3] += (a3 == mx) ? a3 : 0.f;  cn[3] += (a3 == mn);
                cx[4] += (a4 == mx) ? a4 : 0.f;  cn[4] += (a4 == mn);
                cx[5] += (a5 == mx) ? a5 : 0.f;  cn[5] += (a5 == mn);
                cx[6] += (a6 == mx) ? a6 : 0.f;  cn[6] += (a6 == mn);
                cx[7] += (a7 == mx) ? a7 : 0.f;  cn[7] += (a7 == mn);
            }
        }
    }
}

// One WAVE per block: zero barriers, fully independent waves (decorrelated
// stalls). LDS 12 KB/block -> ~13 blocks/CU; VGPR cap 85 (3 waves/EU).
__global__ __launch_bounds__(64, 3) void hydra_kernel(
    const float* __restrict__ X,   // [N, C, L]
    const float* __restrict__ W,   // [D, DIV, K*H, 1, KW]
    const int*   __restrict__ I,   // [D, DIV, H, CP]
    float* __restrict__ out)       // [N, FEAT]
{
    __shared__ __align__(16) float s_conv[3072];

    const int lane  = threadIdx.x;         // 0..63
    // ---- XCD swizzle: XCD k (= b&7) owns n in [16k,16k+16).
    // comb in LOW bits of rem: CU-resident blocks (stride ~32 in sub) share
    // the same comb -> one hot I$ region per CU.
    const int b_raw = blockIdx.x;
    const int xcd   = b_raw & 7;
    const int sub   = b_raw >> 3;          // 0..8191
    const int n     = xcd * 16 + (sub >> 9);
    const int rem   = sub & 511;
    const int comb  = rem & 15;            // di*2 + df
    const int h     = rem >> 4;

    const int df   = comb & 1;
    const int di   = comb >> 1;
    const int d    = 1 << di;
    const int Lsrc = L_ - df;              // 2048 or 2047
    const int pad  = 4 * d;

    // ---- zero pad regions only (in-wave ordering; no barrier needed) ----
    for (int j = lane; j < pad; j += 64)               s_conv[j] = 0.0f;
    for (int j = pad + Lsrc + lane; j < 3072; j += 64) s_conv[j] = 0.0f;

    // block-uniform channel indices (scalarized)
    const int* Ib = I + (comb * H_ + h) * CP_;
    const int c0 = Ib[0], c1 = Ib[1], c2 = Ib[2],
              c3 = Ib[3], c4 = Ib[4], c5 = Ib[5];
    const float* Xn = X + (size_t)n * (C_ * L_);
    const float* xp0 = Xn + c0 * L_;
    const float* xp1 = Xn + c1 * L_;
    const float* xp2 = Xn + c2 * L_;
    const float* xp3 = Xn + c3 * L_;
    const float* xp4 = Xn + c4 * L_;
    const float* xp5 = Xn + c5 * L_;

    // block-uniform weights -> SGPRs
    const float* Wb = W + (size_t)(comb * (K_ * H_) + h * K_) * KW_;
    float wr[K_ * KW_];
    #pragma unroll
    for (int q = 0; q < K_ * KW_; ++q) wr[q] = Wb[q];

    // ---- staging: 4 chunks of 512 positions; 48-load bursts per chunk ----
    #pragma unroll
    for (int c = 0; c < 4; ++c) {
        float sl[8];
        {
            float l0[8], l1[8], l2[8];
            #pragma unroll
            for (int j = 0; j < 8; ++j) {
                const int t = c * 512 + lane + j * 64;
                l0[j] = xp0[t]; l1[j] = xp1[t]; l2[j] = xp2[t];
            }
            #pragma unroll
            for (int j = 0; j < 8; ++j) sl[j] = (l0[j] + l1[j]) + l2[j];
        }
        {
            float l0[8], l1[8], l2[8];
            #pragma unroll
            for (int j = 0; j < 8; ++j) {
                const int t = c * 512 + lane + j * 64;
                l0[j] = xp3[t]; l1[j] = xp4[t]; l2[j] = xp5[t];
            }
            #pragma unroll
            for (int j = 0; j < 8; ++j) sl[j] += (l0[j] + l1[j]) + l2[j];
        }
        #pragma unroll
        for (int j = 0; j < 8; ++j)
            s_conv[pad + c * 512 + lane + j * 64] = sl[j];
    }

    // ---- df=1: in-wave diff, D[t] = S[t+1]-S[t]. All reads precede all
    // writes in the single wave's instruction stream -> no race, no barrier.
    if (df == 1) {
        float dv[32];
        #pragma unroll
        for (int c = 0; c < 4; ++c)
            #pragma unroll
            for (int j = 0; j < 8; ++j) {
                const int t = c * 512 + lane + j * 64;
                dv[c * 8 + j] = s_conv[pad + t + 1] - s_conv[pad + t];
            }
        #pragma unroll
        for (int c = 0; c < 4; ++c)
            #pragma unroll
            for (int j = 0; j < 8; ++j) {
                const int t = c * 512 + lane + j * 64;
                s_conv[pad + t] = (t == 2047) ? 0.0f : dv[c * 8 + j];
            }
    }

    // ---- conv + equality-scatter (templated dilation) ----
    float cx[K_] = {0.f, 0.f, 0.f, 0.f, 0.f, 0.f, 0.f, 0.f};
    int   cn[K_] = {0, 0, 0, 0, 0, 0, 0, 0};

    switch (comb) {
        case  0: conv_phase<  1, false>(s_conv, wr, cx, cn, lane); break;
        case  1: conv_phase<  1, true >(s_conv, wr, cx, cn, lane); break;
        case  2: conv_phase<  2, false>(s_conv, wr, cx, cn, lane); break;
        case  3: conv_phase<  2, true >(s_conv, wr, cx, cn, lane); break;
        case  4: conv_phase<  4, false>(s_conv, wr, cx, cn, lane); break;
        case  5: conv_phase<  4, true >(s_conv, wr, cx, cn, lane); break;
        case  6: conv_phase<  8, false>(s_conv, wr, cx, cn, lane); break;
        case  7: conv_phase<  8, true >(s_conv, wr, cx, cn, lane); break;
        case  8: conv_phase< 16, false>(s_conv, wr, cx, cn, lane); break;
        case  9: conv_phase< 16, true >(s_conv, wr, cx, cn, lane); break;
        case 10: conv_phase< 32, false>(s_conv, wr, cx, cn, lane); break;
        case 11: conv_phase< 32, true >(s_conv, wr, cx, cn, lane); break;
        case 12: conv_phase< 64, false>(s_conv, wr, cx, cn, lane); break;
        case 13: conv_phase< 64, true >(s_conv, wr, cx, cn, lane); break;
        case 14: conv_phase<128, false>(s_conv, wr, cx, cn, lane); break;
        default: conv_phase<128, true >(s_conv, wr, cx, cn, lane); break;
    }

    // ---- pure in-wave butterfly reduction of the 16 accumulators ----
    float red[16];
    #pragma unroll
    for (int k = 0; k < K_; ++k) { red[k] = cx[k]; red[8 + k] = (float)cn[k]; }
    #pragma unroll
    for (int off = 1; off < 64; off <<= 1) {
        #pragma unroll
        for (int q = 0; q < 16; ++q)
            red[q] += __shfl_xor(red[q], off, 64);
    }
    if (lane == 0) {
        float* ob = out + (size_t)n * FEAT_ + (comb * 2) * (H_ * K_) + h * K_;
        #pragma unroll
        for (int k = 0; k < K_; ++k) ob[k] = red[k];               // cmax
        #pragma unroll
        for (int k = 0; k < K_; ++k) ob[H_ * K_ + k] = red[8 + k]; // cmin
    }
}

extern "C" void kernel_launch(void* const* d_in, const int* in_sizes, int n_in,
                              void* d_out, int out_size, void* d_ws, size_t ws_size,
                              hipStream_t stream) {
    const float* X = (const float*)d_in[0];
    const float* W = (const float*)d_in[1];
    const int*   I = (const int*)d_in[2];
    float* out = (float*)d_out;

    const int blocks = N_ * 16 * H_;   // 65536: one wave per (n, comb, h)
    hipLaunchKernelGGL(hydra_kernel, dim3(blocks), dim3(64), 0, stream,
                       X, W, I, out);
}